// Round 8
// baseline (110.178 us; speedup 1.0000x reference)
//
#include <hip/hip_runtime.h>
#include <hip/hip_bf16.h>
#include <stdint.h>

#define NUM_LAYERS 24
#define LN_EPS 1e-5f
#define N_ROWS (256 * 8192)
#define ROWS_PER_ITER 64
#define NUM_ITERS (N_ROWS / ROWS_PER_ITER)   // 32768
#define NUM_BLOCKS 2048                       // 8192 waves -> 4 iters/wave

typedef __attribute__((ext_vector_type(4)))  uint32_t u32x4;   // MFMA A/B operand (4 VGPRs)
typedef __attribute__((ext_vector_type(16))) float    f32x16;  // 32x32 MFMA acc
typedef __attribute__((ext_vector_type(2)))  float    f32x2;
typedef __attribute__((ext_vector_type(2)))  __fp16   h16x2;   // matches cvt_pkrtz return type

// ---- f16 packing helpers ----
__device__ __forceinline__ uint32_t pk_f16_rtz(float lo, float hi) {
    h16x2 v = __builtin_amdgcn_cvt_pkrtz(lo, hi);   // v_cvt_pkrtz_f16_f32
    uint32_t u; __builtin_memcpy(&u, &v, 4);
    return u;
}
__device__ __forceinline__ uint32_t pk_f16_rne(float lo, float hi) {  // setup only
    __fp16 a = (__fp16)lo, b = (__fp16)hi;
    uint16_t ua, ub;
    __builtin_memcpy(&ua, &a, 2); __builtin_memcpy(&ub, &b, 2);
    return (uint32_t)ua | ((uint32_t)ub << 16);
}
// packed relu on 2 f16 (v_pk_max_f16)
__device__ __forceinline__ uint32_t pk_relu_f16(uint32_t d) {
    h16x2 v; __builtin_memcpy(&v, &d, 4);
    h16x2 z = {(__fp16)0.0f, (__fp16)0.0f};
    v = __builtin_elementwise_max(v, z);
    uint32_t u; __builtin_memcpy(&u, &v, 4);
    return u;
}

__device__ __forceinline__ u32x4 make_frag(uint32_t d0, uint32_t d1,
                                           uint32_t d2, uint32_t d3) {
    u32x4 f; f.x = d0; f.y = d1; f.z = d2; f.w = d3;
    return f;
}

// ---- inline-asm MFMA, VGPR form, no AGPR round-trips ----
// s_nop 2 guards the VALU-write -> MFMA-read hazard (asm is opaque to the
// compiler's hazard recognizer). "=&v" earlyclobber keeps D off A/B/C.
__device__ __forceinline__ f32x16 mfma_f16_c(u32x4 a, u32x4 b, const f32x16& c) {
    f32x16 d;
    asm("s_nop 2\n\tv_mfma_f32_32x32x16_f16 %0, %1, %2, %3"
        : "=&v"(d) : "v"(a), "v"(b), "v"(c));
    return d;
}
// C = inline constant 0 (saves a 16-reg zero vector)
__device__ __forceinline__ f32x16 mfma_f16_z(u32x4 a, u32x4 b) {
    f32x16 d;
    asm("s_nop 2\n\tv_mfma_f32_32x32x16_f16 %0, %1, %2, 0"
        : "=&v"(d) : "v"(a), "v"(b));
    return d;
}
__device__ __forceinline__ void mfma_f16_acc(f32x16& c, u32x4 a, u32x4 b) {
    asm("s_nop 2\n\tv_mfma_f32_32x32x16_f16 %0, %1, %2, %0"
        : "+v"(c) : "v"(a), "v"(b));
}
// MFMA-D -> VALU-read fence: 24 cycles of s_nop, data-tied to the acc.
__device__ __forceinline__ void mfma_fence2(f32x16& c0, f32x16& c1) {
    asm volatile("s_nop 7\n\ts_nop 7\n\ts_nop 7" : "+v"(c0), "+v"(c1));
}

// canonical hidden index k placed at layer1-output row-position p (sigma).
// C1 (32x32 C-layout) reg r, lane-half hh, m-tile mt holds position
// p = 32*mt + (r&3) + 8*(r>>2) + 4*hh; that position must carry canonical
// k = 16*(2*mt + (r>>3)) + 8*hh + (r&7) so the layer2 h1-fragment slot
// (kt = 2*mt + (r>>3), j = r&7) is correct for BOTH halves.
__device__ __forceinline__ int sigma_k(int p) {
    int hh = (p >> 2) & 1;
    int base = (p & 31) - 4 * hh;            // in {0-3,8-11,16-19,24-27}
    int r = (base & 3) + 4 * (base >> 3);    // in [0,16)
    return 32 * (p >> 5) + 16 * (r >> 3) + 8 * hh + (r & 7);
}

__global__ __launch_bounds__(256, 4) void router_mfma(
    const float* __restrict__ x,
    const float* __restrict__ ln_w,
    const float* __restrict__ ln_b,
    const float* __restrict__ W1,
    const float* __restrict__ b1,
    const float* __restrict__ W2,
    const float* __restrict__ b2,
    const float* __restrict__ W3,
    const float* __restrict__ b3,
    float* __restrict__ out)
{
    // ln_w/ln_b interleaved per lid: [g0..g3, b0..b3] (32B per lid)
    __shared__ float s_ln[NUM_LAYERS * 8];
    const int t = threadIdx.x;
    if (t < NUM_LAYERS * 4) {
        int lid = t >> 2, c = t & 3;
        s_ln[lid * 8 + c]     = ln_w[t];
        s_ln[lid * 8 + 4 + c] = ln_b[t];
    }
    __syncthreads();

    const int lane = t & 63;
    const int wid  = t >> 6;
    const int n32  = lane & 31;
    const int h    = lane >> 5;

    // ---------- preload weight fragments (once per thread, RNE) ----------
    // Layer1 A-frags: A[p][q]: q<5 = W1[k][q], q==5 = b1[k], rest 0.
    // h=1 lanes (K columns 8..15) are ZERO -> B-operand needs no lane zeroing.
    u32x4 a1f[2];
#pragma unroll
    for (int mt = 0; mt < 2; ++mt) {
        int p = mt * 32 + n32;
        int k = sigma_k(p);
        uint32_t d0 = pk_f16_rne(W1[k * 5 + 0], W1[k * 5 + 1]);
        uint32_t d1 = pk_f16_rne(W1[k * 5 + 2], W1[k * 5 + 3]);
        uint32_t d2 = pk_f16_rne(W1[k * 5 + 4], b1[k]);
        if (h) { d0 = 0; d1 = 0; d2 = 0; }
        a1f[mt] = make_frag(d0, d1, d2, 0);
    }

    // Layer2 W2-frags (4 k-tiles), A operand of C2^T = W2·h1^T.
    u32x4 w2f[4];
#pragma unroll
    for (int kt = 0; kt < 4; ++kt) {
        const float* wp = W2 + n32 * 64 + kt * 16 + h * 8;
        const float4 lo = *(const float4*)(wp);
        const float4 hi = *(const float4*)(wp + 4);
        w2f[kt] = make_frag(pk_f16_rne(lo.x, lo.y), pk_f16_rne(lo.z, lo.w),
                            pk_f16_rne(hi.x, hi.y), pk_f16_rne(hi.z, hi.w));
    }

    // C2^T C-layout: lane = data-row, reg r -> out-unit n = (r&3)+8*(r>>2)+4*h
    // b2 folded into the layer-2 chain-A C-init tuple (loop-invariant).
    f32x16 c2init;
    f32x2 w3p[8];
#pragma unroll
    for (int r2 = 0; r2 < 8; ++r2) {
        const int n = ((2 * r2) & 3) + 8 * (r2 >> 1) + 4 * h;
        w3p[r2] = f32x2{W3[n], W3[n + 1]};
        c2init[2 * r2]     = b2[n];
        c2init[2 * r2 + 1] = b2[n + 1];
    }
    const float b3v = b3[0];
    const f32x2 z2 = {0.0f, 0.0f};

    const int total_waves = NUM_BLOCKS * 4;
    const int w = blockIdx.x * 4 + wid;

    // ---- software-pipelined row loop; each lane LNs ONE distinct row ----
    int it = w;
    const float* xp0 = x + (size_t)(it * ROWS_PER_ITER + lane) * 5;
    float f0 = xp0[0], f1 = xp0[1], f2 = xp0[2], f3 = xp0[3], lp = xp0[4];

    while (true) {
        const int nit = it + total_waves;
        const bool more = nit < NUM_ITERS;
        const float* nxp =
            x + (size_t)((more ? nit : it) * ROWS_PER_ITER + lane) * 5;
        const float nf0 = nxp[0], nf1 = nxp[1], nf2 = nxp[2], nf3 = nxp[3],
                    nlp = nxp[4];

        const int rowBase = it * ROWS_PER_ITER;

        // ---- LayerNorm of row (rowBase + lane) ----
        int lid = (int)(lp * (float)NUM_LAYERS);
        lid = lid < 0 ? 0 : (lid > NUM_LAYERS - 1 ? NUM_LAYERS - 1 : lid);

        const float m  = (f0 + f1 + f2 + f3) * 0.25f;
        const float d0 = f0 - m, d1 = f1 - m, d2 = f2 - m, d3 = f3 - m;
        const float var = (d0 * d0 + d1 * d1 + d2 * d2 + d3 * d3) * 0.25f;
        const float r   = rsqrtf(var + LN_EPS);

        const float4 g  = *(const float4*)(s_ln + lid * 8);
        const float4 bb = *(const float4*)(s_ln + lid * 8 + 4);

        const float xn0 = fmaf(d0 * r, g.x, bb.x);
        const float xn1 = fmaf(d1 * r, g.y, bb.y);
        const float xn2 = fmaf(d2 * r, g.z, bb.z);
        const float xn3 = fmaf(d3 * r, g.w, bb.w);

        // packed normed features (+ 1.0 slot at q=5 for the b1 fold).
        // No lane zeroing needed: A's k>=8 columns are zero.
        const uint32_t e0 = pk_f16_rtz(xn0, xn1);
        const uint32_t e1 = pk_f16_rtz(xn2, xn3);
        const uint32_t e2 = pk_f16_rtz(lp, 1.0f);
        const uint32_t x0 = __shfl_xor((int)e0, 32, 64);
        const uint32_t x1 = __shfl_xor((int)e1, 32, 64);
        const uint32_t x2 = __shfl_xor((int)e2, 32, 64);

        const u32x4 bf_t0 = make_frag(e0, e1, e2, 0u);  // rows 0..31 (h=0 half)
        const u32x4 bf_t1 = make_frag(x0, x1, x2, 0u);  // rows 32..63

        float res[2];
#pragma unroll
        for (int tile = 0; tile < 2; ++tile) {
            const u32x4 b1f = tile ? bf_t1 : bf_t0;

            // layer 1: h1^T = A1 . xn^T (2 MFMAs, C = inline 0)
            f32x16 c1a = mfma_f16_z(a1f[0], b1f);
            f32x16 c1b = mfma_f16_z(a1f[1], b1f);
            mfma_fence2(c1a, c1b);

            // pack-then-relu repack into h1 fragments (lane=row, k along regs)
            u32x4 h1f[4];
#pragma unroll
            for (int kt = 0; kt < 4; ++kt) {
                const f32x16& c1 = (kt < 2) ? c1a : c1b;
                const int roff = 8 * (kt & 1);
                uint32_t dw[4];
#pragma unroll
                for (int d = 0; d < 4; ++d)
                    dw[d] = pk_relu_f16(
                        pk_f16_rtz(c1[roff + 2 * d], c1[roff + 2 * d + 1]));
                h1f[kt] = make_frag(dw[0], dw[1], dw[2], dw[3]);
            }

            // layer 2 transposed: C2^T = W2 . h1^T + b2
            // two independent 2-MFMA chains (halved serial latency)
            f32x16 c2a = mfma_f16_c(w2f[0], h1f[0], c2init);
            f32x16 c2b = mfma_f16_z(w2f[1], h1f[1]);
            mfma_f16_acc(c2a, w2f[2], h1f[2]);
            mfma_f16_acc(c2b, w2f[3], h1f[3]);
            mfma_fence2(c2a, c2b);

            // layer 3: merge chains -> relu -> dot W3 over 16 regs (f32)
            f32x2 acc = z2;
#pragma unroll
            for (int r2 = 0; r2 < 8; ++r2) {
                f32x2 v = {c2a[2 * r2] + c2b[2 * r2],
                           c2a[2 * r2 + 1] + c2b[2 * r2 + 1]};
                v = __builtin_elementwise_max(v, z2);
                acc = v * w3p[r2] + acc;
            }
            float part = acc.x + acc.y;
            part += __shfl_xor(part, 32, 64);
            res[tile] = part;
        }

        // lane stores its own row: h=0 lanes tile0 row n32, h=1 tile1 row n32
        out[rowBase + lane] = (h ? res[1] : res[0]) + b3v;

        if (!more) break;
        it = nit;
        f0 = nf0; f1 = nf1; f2 = nf2; f3 = nf3; lp = nlp;
    }
}

extern "C" void kernel_launch(void* const* d_in, const int* in_sizes, int n_in,
                              void* d_out, int out_size, void* d_ws, size_t ws_size,
                              hipStream_t stream) {
    const float* x    = (const float*)d_in[0];
    const float* ln_w = (const float*)d_in[1];
    const float* ln_b = (const float*)d_in[2];
    const float* W1   = (const float*)d_in[3];
    const float* b1   = (const float*)d_in[4];
    const float* W2   = (const float*)d_in[5];
    const float* b2   = (const float*)d_in[6];
    const float* W3   = (const float*)d_in[7];
    const float* b3   = (const float*)d_in[8];
    float* out = (float*)d_out;

    router_mfma<<<NUM_BLOCKS, 256, 0, stream>>>(x, ln_w, ln_b, W1, b1, W2, b2,
                                                W3, b3, out);
}

// Round 9
// 108.788 us; speedup vs baseline: 1.0128x; 1.0128x over previous
//
#include <hip/hip_runtime.h>
#include <hip/hip_bf16.h>
#include <stdint.h>

#define NUM_LAYERS 24
#define LN_EPS 1e-5f
#define N_ROWS (256 * 8192)
#define ROWS_PER_ITER 64
#define NUM_ITERS (N_ROWS / ROWS_PER_ITER)   // 32768
#define NUM_BLOCKS 768                        // 3 blocks/CU, single batch

typedef __attribute__((ext_vector_type(4)))  uint32_t u32x4;   // MFMA A/B operand
typedef __attribute__((ext_vector_type(16))) float    f32x16;  // 32x32 MFMA acc
typedef __attribute__((ext_vector_type(2)))  float    f32x2;
typedef __attribute__((ext_vector_type(2)))  __fp16   h16x2;

// ---- f16 packing helpers ----
__device__ __forceinline__ uint32_t pk_f16_rtz(float lo, float hi) {
    h16x2 v = __builtin_amdgcn_cvt_pkrtz(lo, hi);   // v_cvt_pkrtz_f16_f32
    uint32_t u; __builtin_memcpy(&u, &v, 4);
    return u;
}
__device__ __forceinline__ uint32_t pk_f16_rne(float lo, float hi) {  // setup only
    __fp16 a = (__fp16)lo, b = (__fp16)hi;
    uint16_t ua, ub;
    __builtin_memcpy(&ua, &a, 2); __builtin_memcpy(&ub, &b, 2);
    return (uint32_t)ua | ((uint32_t)ub << 16);
}
__device__ __forceinline__ uint32_t pk_relu_f16(uint32_t d) {  // v_pk_max_f16
    h16x2 v; __builtin_memcpy(&v, &d, 4);
    h16x2 z = {(__fp16)0.0f, (__fp16)0.0f};
    v = __builtin_elementwise_max(v, z);
    uint32_t u; __builtin_memcpy(&u, &v, 4);
    return u;
}

__device__ __forceinline__ u32x4 make_frag(uint32_t d0, uint32_t d1,
                                           uint32_t d2, uint32_t d3) {
    u32x4 f; f.x = d0; f.y = d1; f.z = d2; f.w = d3;
    return f;
}

// ---- inline-asm MFMA, VGPR form (no AGPR round-trips) ----
__device__ __forceinline__ f32x16 mfma_f16_c(u32x4 a, u32x4 b, const f32x16& c) {
    f32x16 d;
    asm("s_nop 2\n\tv_mfma_f32_32x32x16_f16 %0, %1, %2, %3"
        : "=&v"(d) : "v"(a), "v"(b), "v"(c));
    return d;
}
__device__ __forceinline__ f32x16 mfma_f16_z(u32x4 a, u32x4 b) {  // C = inline 0
    f32x16 d;
    asm("s_nop 2\n\tv_mfma_f32_32x32x16_f16 %0, %1, %2, 0"
        : "=&v"(d) : "v"(a), "v"(b));
    return d;
}
__device__ __forceinline__ void mfma_f16_acc(f32x16& c, u32x4 a, u32x4 b) {
    asm("s_nop 2\n\tv_mfma_f32_32x32x16_f16 %0, %1, %2, %0"
        : "+v"(c) : "v"(a), "v"(b));
}
// MFMA-D -> VALU-read fences (24 cyc), data-tied to the accumulators.
__device__ __forceinline__ void mfma_fence2(f32x16& c0, f32x16& c1) {
    asm volatile("s_nop 7\n\ts_nop 7\n\ts_nop 7" : "+v"(c0), "+v"(c1));
}
__device__ __forceinline__ void mfma_fence4(f32x16& c0, f32x16& c1,
                                            f32x16& c2, f32x16& c3) {
    asm volatile("s_nop 7\n\ts_nop 7\n\ts_nop 7"
                 : "+v"(c0), "+v"(c1), "+v"(c2), "+v"(c3));
}

// canonical hidden index k placed at layer1-output row-position p (sigma) —
// makes C1's C-layout register order equal the layer2 A/B-fragment K order.
__device__ __forceinline__ int sigma_k(int p) {
    int hh = (p >> 2) & 1;
    int base = (p & 31) - 4 * hh;            // {0-3,8-11,16-19,24-27}
    int r = (base & 3) + 4 * (base >> 3);    // [0,16)
    return 32 * (p >> 5) + 16 * (r >> 3) + 8 * hh + (r & 7);
}

__global__ __launch_bounds__(256, 3) void router_mfma(
    const float* __restrict__ x,
    const float* __restrict__ ln_w,
    const float* __restrict__ ln_b,
    const float* __restrict__ W1,
    const float* __restrict__ b1,
    const float* __restrict__ W2,
    const float* __restrict__ b2,
    const float* __restrict__ W3,
    const float* __restrict__ b3,
    float* __restrict__ out)
{
    // ln_w/ln_b interleaved per lid: [g0..g3, b0..b3] (32B per lid)
    __shared__ float s_ln[NUM_LAYERS * 8];
    const int t = threadIdx.x;
    if (t < NUM_LAYERS * 4) {
        int lid = t >> 2, c = t & 3;
        s_ln[lid * 8 + c]     = ln_w[t];
        s_ln[lid * 8 + 4 + c] = ln_b[t];
    }
    __syncthreads();

    const int lane = t & 63;
    const int wid  = t >> 6;
    const int n32  = lane & 31;
    const int h    = lane >> 5;

    // ---------- preload weight fragments ----------
    u32x4 a1f[2];
#pragma unroll
    for (int mt = 0; mt < 2; ++mt) {
        int p = mt * 32 + n32;
        int k = sigma_k(p);
        uint32_t d0 = pk_f16_rne(W1[k * 5 + 0], W1[k * 5 + 1]);
        uint32_t d1 = pk_f16_rne(W1[k * 5 + 2], W1[k * 5 + 3]);
        uint32_t d2 = pk_f16_rne(W1[k * 5 + 4], b1[k]);
        if (h) { d0 = 0; d1 = 0; d2 = 0; }
        a1f[mt] = make_frag(d0, d1, d2, 0);
    }

    u32x4 w2f[4];
#pragma unroll
    for (int kt = 0; kt < 4; ++kt) {
        const float* wp = W2 + n32 * 64 + kt * 16 + h * 8;
        const float4 lo = *(const float4*)(wp);
        const float4 hi = *(const float4*)(wp + 4);
        w2f[kt] = make_frag(pk_f16_rne(lo.x, lo.y), pk_f16_rne(lo.z, lo.w),
                            pk_f16_rne(hi.x, hi.y), pk_f16_rne(hi.z, hi.w));
    }

    // C2^T C-layout: lane = data-row, reg r -> out-unit n = (r&3)+8*(r>>2)+4*h
    f32x16 c2init;
    f32x2 w3p[8];
#pragma unroll
    for (int r2 = 0; r2 < 8; ++r2) {
        const int n = ((2 * r2) & 3) + 8 * (r2 >> 1) + 4 * h;
        w3p[r2] = f32x2{W3[n], W3[n + 1]};
        c2init[2 * r2]     = b2[n];
        c2init[2 * r2 + 1] = b2[n + 1];
    }
    const float b3v = b3[0];
    const f32x2 z2 = {0.0f, 0.0f};

    const int total_waves = NUM_BLOCKS * 4;   // 3072
    const int w = blockIdx.x * 4 + wid;

    // ---- software-pipelined row loop; each lane LNs ONE distinct row ----
    int it = w;
    const float* xp0 = x + (size_t)(it * ROWS_PER_ITER + lane) * 5;
    float f0 = xp0[0], f1 = xp0[1], f2 = xp0[2], f3 = xp0[3], lp = xp0[4];

    while (true) {
        const int nit = it + total_waves;
        const bool more = nit < NUM_ITERS;
        const float* nxp =
            x + (size_t)((more ? nit : it) * ROWS_PER_ITER + lane) * 5;
        const float nf0 = nxp[0], nf1 = nxp[1], nf2 = nxp[2], nf3 = nxp[3],
                    nlp = nxp[4];

        const int rowBase = it * ROWS_PER_ITER;

        // ---- LayerNorm of row (rowBase + lane) ----
        int lid = (int)(lp * (float)NUM_LAYERS);
        lid = lid < 0 ? 0 : (lid > NUM_LAYERS - 1 ? NUM_LAYERS - 1 : lid);

        const float m  = (f0 + f1 + f2 + f3) * 0.25f;
        const float d0 = f0 - m, d1 = f1 - m, d2 = f2 - m, d3 = f3 - m;
        const float var = (d0 * d0 + d1 * d1 + d2 * d2 + d3 * d3) * 0.25f;
        const float r   = rsqrtf(var + LN_EPS);

        const float4 g  = *(const float4*)(s_ln + lid * 8);
        const float4 bb = *(const float4*)(s_ln + lid * 8 + 4);

        const float xn0 = fmaf(d0 * r, g.x, bb.x);
        const float xn1 = fmaf(d1 * r, g.y, bb.y);
        const float xn2 = fmaf(d2 * r, g.z, bb.z);
        const float xn3 = fmaf(d3 * r, g.w, bb.w);

        // packed normed features (+ 1.0 slot at q=5 for the b1 fold)
        const uint32_t e0 = pk_f16_rtz(xn0, xn1);
        const uint32_t e1 = pk_f16_rtz(xn2, xn3);
        const uint32_t e2 = pk_f16_rtz(lp, 1.0f);
        const uint32_t x0 = __shfl_xor((int)e0, 32, 64);
        const uint32_t x1 = __shfl_xor((int)e1, 32, 64);
        const uint32_t x2 = __shfl_xor((int)e2, 32, 64);

        const u32x4 bf_t0 = make_frag(e0, e1, e2, 0u);  // rows 0..31
        const u32x4 bf_t1 = make_frag(x0, x1, x2, 0u);  // rows 32..63

        // ---- Phase A: layer 1, BOTH tiles (4 independent MFMAs) ----
        f32x16 c1a0 = mfma_f16_z(a1f[0], bf_t0);
        f32x16 c1b0 = mfma_f16_z(a1f[1], bf_t0);
        f32x16 c1a1 = mfma_f16_z(a1f[0], bf_t1);
        f32x16 c1b1 = mfma_f16_z(a1f[1], bf_t1);
        mfma_fence4(c1a0, c1b0, c1a1, c1b1);

        // ---- Phase B: repack both tiles (tile0 first frees its c1 regs) ----
        u32x4 h1f0[4], h1f1[4];
#pragma unroll
        for (int kt = 0; kt < 4; ++kt) {
            const f32x16& c1 = (kt < 2) ? c1a0 : c1b0;
            const int roff = 8 * (kt & 1);
            uint32_t dw[4];
#pragma unroll
            for (int d = 0; d < 4; ++d)
                dw[d] = pk_relu_f16(
                    pk_f16_rtz(c1[roff + 2 * d], c1[roff + 2 * d + 1]));
            h1f0[kt] = make_frag(dw[0], dw[1], dw[2], dw[3]);
        }
#pragma unroll
        for (int kt = 0; kt < 4; ++kt) {
            const f32x16& c1 = (kt < 2) ? c1a1 : c1b1;
            const int roff = 8 * (kt & 1);
            uint32_t dw[4];
#pragma unroll
            for (int d = 0; d < 4; ++d)
                dw[d] = pk_relu_f16(
                    pk_f16_rtz(c1[roff + 2 * d], c1[roff + 2 * d + 1]));
            h1f1[kt] = make_frag(dw[0], dw[1], dw[2], dw[3]);
        }

        // ---- Phase C: layer 2, two independent 4-MFMA chains interleaved ----
        f32x16 c2_0 = mfma_f16_c(w2f[0], h1f0[0], c2init);
        f32x16 c2_1 = mfma_f16_c(w2f[0], h1f1[0], c2init);
#pragma unroll
        for (int kt = 1; kt < 4; ++kt) {
            mfma_f16_acc(c2_0, w2f[kt], h1f0[kt]);
            mfma_f16_acc(c2_1, w2f[kt], h1f1[kt]);
        }
        mfma_fence2(c2_0, c2_1);

        // ---- Phase D: epilogue, both tiles overlapped ----
        f32x2 acc0 = z2, acc1 = z2;
#pragma unroll
        for (int r2 = 0; r2 < 8; ++r2) {
            f32x2 v0 = {c2_0[2 * r2], c2_0[2 * r2 + 1]};
            f32x2 v1 = {c2_1[2 * r2], c2_1[2 * r2 + 1]};
            v0 = __builtin_elementwise_max(v0, z2);
            v1 = __builtin_elementwise_max(v1, z2);
            acc0 = v0 * w3p[r2] + acc0;
            acc1 = v1 * w3p[r2] + acc1;
        }
        float p0 = acc0.x + acc0.y;
        float p1 = acc1.x + acc1.y;
        p0 += __shfl_xor(p0, 32, 64);
        p1 += __shfl_xor(p1, 32, 64);

        out[rowBase + lane] = (h ? p1 : p0) + b3v;

        if (!more) break;
        it = nit;
        f0 = nf0; f1 = nf1; f2 = nf2; f3 = nf3; lp = nlp;
    }
}

extern "C" void kernel_launch(void* const* d_in, const int* in_sizes, int n_in,
                              void* d_out, int out_size, void* d_ws, size_t ws_size,
                              hipStream_t stream) {
    const float* x    = (const float*)d_in[0];
    const float* ln_w = (const float*)d_in[1];
    const float* ln_b = (const float*)d_in[2];
    const float* W1   = (const float*)d_in[3];
    const float* b1   = (const float*)d_in[4];
    const float* W2   = (const float*)d_in[5];
    const float* b2   = (const float*)d_in[6];
    const float* W3   = (const float*)d_in[7];
    const float* b3   = (const float*)d_in[8];
    float* out = (float*)d_out;

    router_mfma<<<NUM_BLOCKS, 256, 0, stream>>>(x, ln_w, ln_b, W1, b1, W2, b2,
                                                W3, b3, out);
}

// Round 10
// 108.315 us; speedup vs baseline: 1.0172x; 1.0044x over previous
//
#include <hip/hip_runtime.h>
#include <stdint.h>

#define NUM_LAYERS 24
#define LN_EPS 1e-5f
#define N_ROWS (256 * 8192)
#define ROWS_PER_ITER 64
#define NUM_ITERS (N_ROWS / ROWS_PER_ITER)   // 32768
#define NUM_BLOCKS 2048                       // 4 iters/wave, balanced

typedef __attribute__((ext_vector_type(4)))  uint32_t u32x4;   // MFMA A/B operand
typedef __attribute__((ext_vector_type(16))) float    f32x16;  // 32x32 MFMA acc
typedef __attribute__((ext_vector_type(2)))  float    f32x2;
typedef __attribute__((ext_vector_type(2)))  __fp16   h16x2;

// ---- f16 packing helpers ----
__device__ __forceinline__ uint32_t pk_f16_rtz(float lo, float hi) {
    h16x2 v = __builtin_amdgcn_cvt_pkrtz(lo, hi);   // v_cvt_pkrtz_f16_f32
    uint32_t u; __builtin_memcpy(&u, &v, 4);
    return u;
}
__device__ __forceinline__ uint32_t pk_f16_rne(float lo, float hi) {  // setup only
    __fp16 a = (__fp16)lo, b = (__fp16)hi;
    uint16_t ua, ub;
    __builtin_memcpy(&ua, &a, 2); __builtin_memcpy(&ub, &b, 2);
    return (uint32_t)ua | ((uint32_t)ub << 16);
}
__device__ __forceinline__ uint32_t pk_relu_f16(uint32_t d) {  // v_pk_max_f16
    h16x2 v; __builtin_memcpy(&v, &d, 4);
    h16x2 z = {(__fp16)0.0f, (__fp16)0.0f};
    v = __builtin_elementwise_max(v, z);
    uint32_t u; __builtin_memcpy(&u, &v, 4);
    return u;
}

__device__ __forceinline__ u32x4 make_frag(uint32_t d0, uint32_t d1,
                                           uint32_t d2, uint32_t d3) {
    u32x4 f; f.x = d0; f.y = d1; f.z = d2; f.w = d3;
    return f;
}

// ---- phase-level inline-asm MFMA blocks (VGPR form, single s_nop guard) ----
// Layer 1: 4 independent MFMAs, C = inline 0.
__device__ __forceinline__ void mfma_l1(f32x16& d0, f32x16& d1,
                                        f32x16& d2, f32x16& d3,
                                        const u32x4& a0, const u32x4& a1,
                                        const u32x4& b0, const u32x4& b1) {
    asm("s_nop 2\n\t"
        "v_mfma_f32_32x32x16_f16 %0, %4, %6, 0\n\t"
        "v_mfma_f32_32x32x16_f16 %1, %5, %6, 0\n\t"
        "v_mfma_f32_32x32x16_f16 %2, %4, %7, 0\n\t"
        "v_mfma_f32_32x32x16_f16 %3, %5, %7, 0"
        : "=&v"(d0), "=&v"(d1), "=&v"(d2), "=&v"(d3)
        : "v"(a0), "v"(a1), "v"(b0), "v"(b1));
}
// Layer 2: two interleaved 4-deep accumulation chains, C-init = cinit (b2).
__device__ __forceinline__ void mfma_l2(f32x16& c0, f32x16& c1, const f32x16& cinit,
                                        const u32x4& w0, const u32x4& w1,
                                        const u32x4& w2, const u32x4& w3,
                                        const u32x4& h00, const u32x4& h01,
                                        const u32x4& h02, const u32x4& h03,
                                        const u32x4& h10, const u32x4& h11,
                                        const u32x4& h12, const u32x4& h13) {
    asm("s_nop 2\n\t"
        "v_mfma_f32_32x32x16_f16 %0, %3, %7, %2\n\t"
        "v_mfma_f32_32x32x16_f16 %1, %3, %11, %2\n\t"
        "v_mfma_f32_32x32x16_f16 %0, %4, %8, %0\n\t"
        "v_mfma_f32_32x32x16_f16 %1, %4, %12, %1\n\t"
        "v_mfma_f32_32x32x16_f16 %0, %5, %9, %0\n\t"
        "v_mfma_f32_32x32x16_f16 %1, %5, %13, %1\n\t"
        "v_mfma_f32_32x32x16_f16 %0, %6, %10, %0\n\t"
        "v_mfma_f32_32x32x16_f16 %1, %6, %14, %1"
        : "=&v"(c0), "=&v"(c1)
        : "v"(cinit), "v"(w0), "v"(w1), "v"(w2), "v"(w3),
          "v"(h00), "v"(h01), "v"(h02), "v"(h03),
          "v"(h10), "v"(h11), "v"(h12), "v"(h13));
}
// MFMA-D -> VALU-read fences (24 cyc), data-tied to the accumulators.
__device__ __forceinline__ void mfma_fence2(f32x16& c0, f32x16& c1) {
    asm volatile("s_nop 7\n\ts_nop 7\n\ts_nop 7" : "+v"(c0), "+v"(c1));
}
__device__ __forceinline__ void mfma_fence4(f32x16& c0, f32x16& c1,
                                            f32x16& c2, f32x16& c3) {
    asm volatile("s_nop 7\n\ts_nop 7\n\ts_nop 7"
                 : "+v"(c0), "+v"(c1), "+v"(c2), "+v"(c3));
}

// canonical hidden index k placed at layer1-output row-position p (sigma) —
// makes C1's C-layout register order equal the layer2 fragment K order.
__device__ __forceinline__ int sigma_k(int p) {
    int hh = (p >> 2) & 1;
    int base = (p & 31) - 4 * hh;            // {0-3,8-11,16-19,24-27}
    int r = (base & 3) + 4 * (base >> 3);    // [0,16)
    return 32 * (p >> 5) + 16 * (r >> 3) + 8 * hh + (r & 7);
}

__global__ __launch_bounds__(256, 3) void router_mfma(
    const float* __restrict__ x,
    const float* __restrict__ ln_w,
    const float* __restrict__ ln_b,
    const float* __restrict__ W1,
    const float* __restrict__ b1,
    const float* __restrict__ W2,
    const float* __restrict__ b2,
    const float* __restrict__ W3,
    const float* __restrict__ b3,
    float* __restrict__ out)
{
    // γ/β plane-major: s_ln[q*24 + lid], q=0..3 gamma, 4..7 beta.
    // Per-row gather = 8 conflict-free ds_read_b32 (lid < 24 < 32 banks;
    // same-lid lanes broadcast). Kills the 883k SQ_LDS_BANK_CONFLICT.
    __shared__ float s_ln[8 * NUM_LAYERS];
    // Wave-private x staging: coalesced global loads -> LDS -> stride-5
    // readback (gcd(5,32)=1 => conflict-free).
    __shared__ float s_x[4][ROWS_PER_ITER * 5];

    const int t = threadIdx.x;
    if (t < 8 * NUM_LAYERS) {
        const int q = t & 7, lid = t >> 3;
        s_ln[q * NUM_LAYERS + lid] =
            (q < 4) ? ln_w[lid * 4 + q] : ln_b[lid * 4 + (q - 4)];
    }
    __syncthreads();

    const int lane = t & 63;
    const int wid  = t >> 6;
    const int n32  = lane & 31;
    const int h    = lane >> 5;

    // ---------- preload weight fragments ----------
    u32x4 a1f[2];
#pragma unroll
    for (int mt = 0; mt < 2; ++mt) {
        int p = mt * 32 + n32;
        int k = sigma_k(p);
        uint32_t d0 = pk_f16_rne(W1[k * 5 + 0], W1[k * 5 + 1]);
        uint32_t d1 = pk_f16_rne(W1[k * 5 + 2], W1[k * 5 + 3]);
        uint32_t d2 = pk_f16_rne(W1[k * 5 + 4], b1[k]);
        if (h) { d0 = 0; d1 = 0; d2 = 0; }   // A cols k>=8 are zero
        a1f[mt] = make_frag(d0, d1, d2, 0);
    }

    u32x4 w2f[4];
#pragma unroll
    for (int kt = 0; kt < 4; ++kt) {
        const float* wp = W2 + n32 * 64 + kt * 16 + h * 8;
        const float4 lo = *(const float4*)(wp);
        const float4 hi = *(const float4*)(wp + 4);
        w2f[kt] = make_frag(pk_f16_rne(lo.x, lo.y), pk_f16_rne(lo.z, lo.w),
                            pk_f16_rne(hi.x, hi.y), pk_f16_rne(hi.z, hi.w));
    }

    // C2^T C-layout: lane = data-row, reg r -> out-unit n = (r&3)+8*(r>>2)+4*h
    f32x16 c2init;
    f32x2 w3p[8];
#pragma unroll
    for (int r2 = 0; r2 < 8; ++r2) {
        const int n = ((2 * r2) & 3) + 8 * (r2 >> 1) + 4 * h;
        w3p[r2] = f32x2{W3[n], W3[n + 1]};
        c2init[2 * r2]     = b2[n];
        c2init[2 * r2 + 1] = b2[n + 1];
    }
    const float b3v = b3[0];
    const f32x2 z2 = {0.0f, 0.0f};

    const int total_waves = NUM_BLOCKS * 4;   // 8192
    const int w = blockIdx.x * 4 + wid;

    float* const sx = &s_x[wid][0];
    const float* const sxr = sx + 5 * lane;

    // ---- prologue: stage iter-0 rows ----
    int it = w;
    {
        const float* xg = x + (size_t)it * (ROWS_PER_ITER * 5);
        float ld[5];
#pragma unroll
        for (int j = 0; j < 5; ++j) ld[j] = xg[j * 64 + lane];
#pragma unroll
        for (int j = 0; j < 5; ++j) sx[j * 64 + lane] = ld[j];
    }
    float f0 = sxr[0], f1 = sxr[1], f2 = sxr[2], f3 = sxr[3], lp = sxr[4];

    while (true) {
        const int nit = it + total_waves;
        const bool more = nit < NUM_ITERS;
        // issue next iter's coalesced loads (vmcnt drained at the tail write)
        const float* xg = x + (size_t)(more ? nit : it) * (ROWS_PER_ITER * 5);
        float ld[5];
#pragma unroll
        for (int j = 0; j < 5; ++j) ld[j] = xg[j * 64 + lane];

        const int rowBase = it * ROWS_PER_ITER;

        // ---- LayerNorm of row (rowBase + lane) ----
        int lid = (int)(lp * (float)NUM_LAYERS);
        lid = lid < 0 ? 0 : (lid > NUM_LAYERS - 1 ? NUM_LAYERS - 1 : lid);

        const float m  = (f0 + f1 + f2 + f3) * 0.25f;
        const float d0 = f0 - m, d1 = f1 - m, d2 = f2 - m, d3 = f3 - m;
        const float var = (d0 * d0 + d1 * d1 + d2 * d2 + d3 * d3) * 0.25f;
#if __has_builtin(__builtin_amdgcn_rsqf)
        const float r = __builtin_amdgcn_rsqf(var + LN_EPS);
#else
        const float r = rsqrtf(var + LN_EPS);
#endif
        // conflict-free γ/β gather (8x ds_read_b32, broadcast on same lid)
        const float rg0 = r * s_ln[0 * 24 + lid];
        const float rg1 = r * s_ln[1 * 24 + lid];
        const float rg2 = r * s_ln[2 * 24 + lid];
        const float rg3 = r * s_ln[3 * 24 + lid];
        const float xn0 = fmaf(d0, rg0, s_ln[4 * 24 + lid]);
        const float xn1 = fmaf(d1, rg1, s_ln[5 * 24 + lid]);
        const float xn2 = fmaf(d2, rg2, s_ln[6 * 24 + lid]);
        const float xn3 = fmaf(d3, rg3, s_ln[7 * 24 + lid]);

        // packed normed features (+ 1.0 slot at q=5 for the b1 fold)
        const uint32_t e0 = pk_f16_rtz(xn0, xn1);
        const uint32_t e1 = pk_f16_rtz(xn2, xn3);
        const uint32_t e2 = pk_f16_rtz(lp, 1.0f);
        const uint32_t x0 = __shfl_xor((int)e0, 32, 64);
        const uint32_t x1 = __shfl_xor((int)e1, 32, 64);
        const uint32_t x2 = __shfl_xor((int)e2, 32, 64);

        const u32x4 bf_t0 = make_frag(e0, e1, e2, 0u);  // rows 0..31
        const u32x4 bf_t1 = make_frag(x0, x1, x2, 0u);  // rows 32..63

        // ---- layer 1: both tiles, one asm block ----
        f32x16 c1a0, c1b0, c1a1, c1b1;
        mfma_l1(c1a0, c1b0, c1a1, c1b1, a1f[0], a1f[1], bf_t0, bf_t1);
        mfma_fence4(c1a0, c1b0, c1a1, c1b1);

        // ---- repack both tiles (cvt_pkrtz + pk_max_f16 per dword) ----
        u32x4 h1f0[4], h1f1[4];
#pragma unroll
        for (int kt = 0; kt < 4; ++kt) {
            const f32x16& c1 = (kt < 2) ? c1a0 : c1b0;
            const int roff = 8 * (kt & 1);
            uint32_t dw[4];
#pragma unroll
            for (int d = 0; d < 4; ++d)
                dw[d] = pk_relu_f16(
                    pk_f16_rtz(c1[roff + 2 * d], c1[roff + 2 * d + 1]));
            h1f0[kt] = make_frag(dw[0], dw[1], dw[2], dw[3]);
        }
#pragma unroll
        for (int kt = 0; kt < 4; ++kt) {
            const f32x16& c1 = (kt < 2) ? c1a1 : c1b1;
            const int roff = 8 * (kt & 1);
            uint32_t dw[4];
#pragma unroll
            for (int d = 0; d < 4; ++d)
                dw[d] = pk_relu_f16(
                    pk_f16_rtz(c1[roff + 2 * d], c1[roff + 2 * d + 1]));
            h1f1[kt] = make_frag(dw[0], dw[1], dw[2], dw[3]);
        }

        // ---- layer 2: two interleaved chains, one asm block ----
        f32x16 c2_0, c2_1;
        mfma_l2(c2_0, c2_1, c2init,
                w2f[0], w2f[1], w2f[2], w2f[3],
                h1f0[0], h1f0[1], h1f0[2], h1f0[3],
                h1f1[0], h1f1[1], h1f1[2], h1f1[3]);
        mfma_fence2(c2_0, c2_1);

        // ---- layer 3: relu -> dot W3 over 16 regs, both tiles ----
        f32x2 acc0 = z2, acc1 = z2;
#pragma unroll
        for (int r2 = 0; r2 < 8; ++r2) {
            f32x2 v0 = {c2_0[2 * r2], c2_0[2 * r2 + 1]};
            f32x2 v1 = {c2_1[2 * r2], c2_1[2 * r2 + 1]};
            v0 = __builtin_elementwise_max(v0, z2);
            v1 = __builtin_elementwise_max(v1, z2);
            acc0 = v0 * w3p[r2] + acc0;
            acc1 = v1 * w3p[r2] + acc1;
        }
        float p0 = acc0.x + acc0.y;
        float p1 = acc1.x + acc1.y;
        p0 += __shfl_xor(p0, 32, 64);
        p1 += __shfl_xor(p1, 32, 64);

        out[rowBase + lane] = (h ? p1 : p0) + b3v;

        // ---- stage next iter (wave-private LDS; DS ops are in-order) ----
#pragma unroll
        for (int j = 0; j < 5; ++j) sx[j * 64 + lane] = ld[j];
        f0 = sxr[0]; f1 = sxr[1]; f2 = sxr[2]; f3 = sxr[3]; lp = sxr[4];

        if (!more) break;
        it = nit;
    }
}

extern "C" void kernel_launch(void* const* d_in, const int* in_sizes, int n_in,
                              void* d_out, int out_size, void* d_ws, size_t ws_size,
                              hipStream_t stream) {
    const float* x    = (const float*)d_in[0];
    const float* ln_w = (const float*)d_in[1];
    const float* ln_b = (const float*)d_in[2];
    const float* W1   = (const float*)d_in[3];
    const float* b1   = (const float*)d_in[4];
    const float* W2   = (const float*)d_in[5];
    const float* b2   = (const float*)d_in[6];
    const float* W3   = (const float*)d_in[7];
    const float* b3   = (const float*)d_in[8];
    float* out = (float*)d_out;

    router_mfma<<<NUM_BLOCKS, 256, 0, stream>>>(x, ln_w, ln_b, W1, b1, W2, b2,
                                                W3, b3, out);
}